// Round 4
// baseline (143.729 us; speedup 1.0000x reference)
//
#include <hip/hip_runtime.h>

// DCNv2, fp32 in/out, all matmul-shaped work on bf16 MFMA.
// Round 4: channel-blocked x layout [b][y][g4][x][16ch] (g = 16-ch group).
// A wave's 16-px corner gathers for one ch-slice are now x-contiguous 32B
// blocks (coalesced) instead of 128B-strided scatters -> TCP request count
// and line traffic drop ~4-8x on the dominant phase-B gather and phase-A
// im2col. Arithmetic identical to R3 (same pipelined structure, swizzle).
//  - pre_kernel: x NCHW -> xT_hi/xT_lo bf16 blocked-NHWC + weight A-frags
//  - fused_dcn_kernel: offset conv (im2col GEMM, 3-term split-bf16) ->
//    offsets in LDS -> bilinear sample -> LDS B-frags -> deform GEMM.
// ws: xThi 8388608 | xTlo 8388608 | wdA 73728 | woAhi 36864 | woAlo 36864

#define BATCH 4
#define CIN   64
#define COUT  64
#define HH    128
#define WW    128
#define HWPIX (HH*WW)

typedef __attribute__((ext_vector_type(8))) short short8;   // 8 bf16 (4 VGPRs)
typedef __attribute__((ext_vector_type(4))) float floatx4;  // MFMA C/D

__device__ __forceinline__ unsigned short f2bf(float f) {   // RNE f32->bf16
  unsigned int u = __float_as_uint(f);
  unsigned int r = u + 0x7fffu + ((u >> 16) & 1u);
  return (unsigned short)(r >> 16);
}
__device__ __forceinline__ float bf2f(unsigned short h) { return __uint_as_float(((unsigned int)h) << 16); }
__device__ __forceinline__ float lo16f(unsigned int u) { return __uint_as_float(u << 16); }
__device__ __forceinline__ float hi16f(unsigned int u) { return __uint_as_float(u & 0xffff0000u); }

__device__ __forceinline__ unsigned int bilin2(unsigned int u00, unsigned int u01,
                                               unsigned int u10, unsigned int u11,
                                               float w00, float w01, float w10, float w11) {
  float lo = w00 * lo16f(u00) + w01 * lo16f(u01) + w10 * lo16f(u10) + w11 * lo16f(u11);
  float hi = w00 * hi16f(u00) + w01 * hi16f(u01) + w10 * hi16f(u10) + w11 * hi16f(u11);
  return (unsigned int)f2bf(lo) | ((unsigned int)f2bf(hi) << 16);
}

// blocked-NHWC index (in shorts): [y][g][x][16]
__device__ __forceinline__ int xidx(int y, int g, int x) {
  return (((y * 4 + g) * WW) + x) * 16;
}

// LDS byte-offset swizzle: fold bits 9-10 into bits 4-5.
__device__ __forceinline__ int swz(int a) { return a ^ (((a >> 9) & 3) << 4); }

// Fused preprocessing:
//  blocks [0,4096):  x fp32 NCHW -> xThi/xTlo bf16 blocked-NHWC
//  blocks [4096,4312): weight prep
__global__ __launch_bounds__(256) void pre_kernel(const float* __restrict__ x,
                                                  const float* __restrict__ wo,
                                                  const float* __restrict__ wd,
                                                  unsigned short* __restrict__ xThi,
                                                  unsigned short* __restrict__ xTlo,
                                                  unsigned short* __restrict__ wdA,
                                                  unsigned short* __restrict__ woAhi,
                                                  unsigned short* __restrict__ woAlo) {
  int tid = threadIdx.x;
  if (blockIdx.x < 4096) {
    __shared__ float tile[32][33];   // [c_local][p_local]
    int t = blockIdx.x;
    int b = t >> 10, rem = t & 1023;
    int c0 = (rem >> 9) * 32, p0 = (rem & 511) * 32;
    int tx = tid & 31, ty = tid >> 5;      // (32,8)
    const float* xb = x + (size_t)b * CIN * HWPIX;
    size_t boff = (size_t)b * HWPIX * CIN;
    int yy = p0 >> 7, xbase = p0 & 127;    // 32-px chunk lies within one row
#pragma unroll
    for (int i = 0; i < 4; i++)
      tile[ty + i * 8][tx] = xb[(size_t)(c0 + ty + i * 8) * HWPIX + p0 + tx];
    __syncthreads();
#pragma unroll
    for (int i = 0; i < 2; i++) {
      int tt = tid + i * 256;       // 0..511 = 32 x-positions * 16 cin-pairs
      int row = tt >> 4;            // x offset within chunk
      int cp = tt & 15;
      int c = c0 + cp * 2;          // channel (even); pair within one 16-group
      int g = c >> 4, cl = c & 15;
      float v0 = tile[cp * 2][row], v1 = tile[cp * 2 + 1][row];
      unsigned short h0 = f2bf(v0), h1 = f2bf(v1);
      unsigned short l0 = f2bf(v0 - bf2f(h0)), l1 = f2bf(v1 - bf2f(h1));
      size_t o = boff + xidx(yy, g, xbase + row) + cl;
      *(ushort2*)&xThi[o] = make_ushort2(h0, h1);
      *(ushort2*)&xTlo[o] = make_ushort2(l0, l1);
    }
  } else {
    int t = (blockIdx.x - 4096) * 256 + tid;
    if (t < 36864) {
      int j = t & 7, lane = (t >> 3) & 63, ct = (t >> 9) & 3, kc = (t >> 11) & 1, kk = t >> 12;
      int cout = ct * 16 + (lane & 15);
      int cin  = kc * 32 + (lane >> 4) * 8 + j;
      wdA[t] = f2bf(wd[(size_t)(cout * CIN + cin) * 9 + kk]);
    }
    int t2 = t - 36864;
    if (t2 >= 0 && t2 < 18432) {
      int j = t2 & 7, lane = (t2 >> 3) & 63, ct = (t2 >> 9) & 1, kc = (t2 >> 10) & 1, kk = t2 >> 11;
      int cout = ct * 16 + (lane & 15);          // conv channel 0..31 (valid < 18)
      int cin  = kc * 32 + (lane >> 4) * 8 + j;
      float v = (cout < 18) ? wo[(size_t)(cout * CIN + cin) * 9 + kk] : 0.f;
      unsigned short h = f2bf(v);
      woAhi[t2] = h;
      woAlo[t2] = f2bf(v - bf2f(h));
    }
  }
}

// Fused offset-conv + deform GEMM, software-pipelined, blocked-NHWC gathers.
// Block: 64 px tile (b, y, x0..x0+63), 256 thr = 4 waves.
// Staging view: p1 = tid>>2 (px 0..63), si = tid&3 (16-ch group g).
// MFMA view: wave w, lane.
__global__ __launch_bounds__(256) void fused_dcn_kernel(const unsigned short* __restrict__ xThi,
                                                        const unsigned short* __restrict__ xTlo,
                                                        const unsigned short* __restrict__ woAhi,
                                                        const unsigned short* __restrict__ woAlo,
                                                        const unsigned short* __restrict__ wdA,
                                                        float* __restrict__ out) {
  __shared__ unsigned short sBhi[4096];    // 8 KB; A: im2col hi; B: sampled frags
  __shared__ unsigned short sBlo[4096];    // 8 KB; A only: im2col lo
  __shared__ float offL[18 * 64];          // 4.5 KB

  int tid = threadIdx.x;
  int hw = blockIdx.x;
  int bid = (hw & 7) * 128 + (hw >> 3);    // XCD-contiguous y bands
  int b = bid >> 8, r = bid & 255, y = r >> 1, x0 = (r & 1) << 6;

  int p1 = tid >> 2, si = tid & 3;
  int lane = tid & 63, w = tid >> 6;

  const unsigned short* xhib = xThi + (size_t)b * HWPIX * CIN;
  const unsigned short* xlob = xTlo + (size_t)b * HWPIX * CIN;

  // B-frag staging addresses (byte offsets), swizzled once.
  int wq = p1 >> 4, iq = p1 & 15;
  int kcd = si >> 1, qb = si & 1;
  int wb0 = ((((wq * 2 + kcd) * 64) + qb * 32 + iq) * 8) * 2;
  int wb1 = wb0 + 256;
  unsigned short* stHi0 = (unsigned short*)((char*)sBhi + swz(wb0));
  unsigned short* stHi1 = (unsigned short*)((char*)sBhi + swz(wb1));
  unsigned short* stLo0 = (unsigned short*)((char*)sBlo + swz(wb0));
  unsigned short* stLo1 = (unsigned short*)((char*)sBlo + swz(wb1));
  int rb0 = (w * 2 + 0) * 1024 + lane * 16;
  int rb1 = (w * 2 + 1) * 1024 + lane * 16;
  const short8* rdHi0 = (const short8*)((const char*)sBhi + swz(rb0));
  const short8* rdHi1 = (const short8*)((const char*)sBhi + swz(rb1));
  const short8* rdLo0 = (const short8*)((const char*)sBlo + swz(rb0));
  const short8* rdLo1 = (const short8*)((const char*)sBlo + swz(rb1));

  int xp = x0 + p1;

  // ================= Phase A: offset conv (pipelined) =================
  floatx4 oacc[2];
  oacc[0] = (floatx4){0.f, 0.f, 0.f, 0.f};
  oacc[1] = (floatx4){0.f, 0.f, 0.f, 0.f};

  auto ldA = [&](int kk, uint4& h0, uint4& h1, uint4& l0, uint4& l1) {
    int ys = y - 1 + kk / 3;
    int xs = xp - 1 + kk % 3;
    bool valid = (ys >= 0) && (ys < HH) && (xs >= 0) && (xs < WW);
    h0 = (uint4){0, 0, 0, 0}; h1 = h0; l0 = h0; l1 = h0;
    if (valid) {
      const unsigned short* ph = xhib + xidx(ys, si, xs);
      const unsigned short* pl = xlob + xidx(ys, si, xs);
      h0 = *(const uint4*)ph; h1 = *(const uint4*)(ph + 8);
      l0 = *(const uint4*)pl; l1 = *(const uint4*)(pl + 8);
    }
  };
  auto bodyA = [&](int kk, const uint4& h0, const uint4& h1, const uint4& l0, const uint4& l1) {
    // A-frag loads issued first: latency hides under ds_write + barrier.
    const short8* Ah = (const short8*)(woAhi + (size_t)kk * 2048);
    const short8* Al = (const short8*)(woAlo + (size_t)kk * 2048);
    short8 ah0a = Ah[lane],       ah1a = Ah[128 + lane];
    short8 al0a = Al[lane],       al1a = Al[128 + lane];
    short8 ah0b = Ah[64 + lane],  ah1b = Ah[192 + lane];
    short8 al0b = Al[64 + lane],  al1b = Al[192 + lane];
    *(uint4*)stHi0 = h0; *(uint4*)stHi1 = h1;
    *(uint4*)stLo0 = l0; *(uint4*)stLo1 = l1;
    __syncthreads();
    short8 bh0 = *rdHi0, bh1 = *rdHi1;
    short8 bl0 = *rdLo0, bl1 = *rdLo1;
    oacc[0] = __builtin_amdgcn_mfma_f32_16x16x32_bf16(ah0a, bh0, oacc[0], 0, 0, 0);
    oacc[0] = __builtin_amdgcn_mfma_f32_16x16x32_bf16(ah0a, bl0, oacc[0], 0, 0, 0);
    oacc[0] = __builtin_amdgcn_mfma_f32_16x16x32_bf16(al0a, bh0, oacc[0], 0, 0, 0);
    oacc[0] = __builtin_amdgcn_mfma_f32_16x16x32_bf16(ah1a, bh1, oacc[0], 0, 0, 0);
    oacc[0] = __builtin_amdgcn_mfma_f32_16x16x32_bf16(ah1a, bl1, oacc[0], 0, 0, 0);
    oacc[0] = __builtin_amdgcn_mfma_f32_16x16x32_bf16(al1a, bh1, oacc[0], 0, 0, 0);
    oacc[1] = __builtin_amdgcn_mfma_f32_16x16x32_bf16(ah0b, bh0, oacc[1], 0, 0, 0);
    oacc[1] = __builtin_amdgcn_mfma_f32_16x16x32_bf16(ah0b, bl0, oacc[1], 0, 0, 0);
    oacc[1] = __builtin_amdgcn_mfma_f32_16x16x32_bf16(al0b, bh0, oacc[1], 0, 0, 0);
    oacc[1] = __builtin_amdgcn_mfma_f32_16x16x32_bf16(ah1b, bh1, oacc[1], 0, 0, 0);
    oacc[1] = __builtin_amdgcn_mfma_f32_16x16x32_bf16(ah1b, bl1, oacc[1], 0, 0, 0);
    oacc[1] = __builtin_amdgcn_mfma_f32_16x16x32_bf16(al1b, bh1, oacc[1], 0, 0, 0);
    __syncthreads();
  };

  {
    uint4 h0c, h1c, l0c, l1c;
    ldA(0, h0c, h1c, l0c, l1c);
#pragma unroll 1
    for (int kk = 0; kk < 8; kk++) {
      uint4 h0n, h1n, l0n, l1n;
      ldA(kk + 1, h0n, h1n, l0n, l1n);      // issue next-iter loads
      bodyA(kk, h0c, h1c, l0c, l1c);        // consume current (counted vmcnt)
      h0c = h0n; h1c = h1n; l0c = l0n; l1c = l1n;
    }
    bodyA(8, h0c, h1c, l0c, l1c);
  }

  // Scatter offsets to LDS. D layout: col=lane&15 (px), row=(lane>>4)*4+rr.
  // Wave w writes columns [16w,16w+16) and phase B (p1 in [16w,16w+16)) reads
  // only those -> same-wave ordering, no barrier needed.
  {
    int pxl = w * 16 + (lane & 15);
    int rowb = (lane >> 4) * 4;
#pragma unroll
    for (int ct = 0; ct < 2; ct++)
#pragma unroll
      for (int rr = 0; rr < 4; rr++) {
        int row = ct * 16 + rowb + rr;
        if (row < 18) offL[row * 64 + pxl] = oacc[ct][rr];
      }
  }

  // ================= Phase B: deform sample + GEMM (pipelined) =================
  floatx4 acc[4];
#pragma unroll
  for (int ct = 0; ct < 4; ct++) acc[ct] = (floatx4){0.f, 0.f, 0.f, 0.f};

  struct BS {
    float w00, w01, w10, w11;
    uint4 a00, a01, a10, a11, b00, b01, b10, b11;
  };
  auto ldB = [&](int kk) -> BS {
    BS s;
    float dy = offL[(2 * kk) * 64 + p1];
    float dx = offL[(2 * kk + 1) * 64 + p1];
    float ys = (float)(y - 1 + kk / 3) + dy;
    float xs = (float)(xp - 1 + kk % 3) + dx;
    float y0f = floorf(ys), x0f = floorf(xs);
    float wy = ys - y0f, wx = xs - x0f;
    int iy0 = (int)y0f, ix0 = (int)x0f;
    int iy1 = iy0 + 1, ix1 = ix0 + 1;
    s.w00 = (1.f - wy) * (1.f - wx); s.w01 = (1.f - wy) * wx;
    s.w10 = wy * (1.f - wx);         s.w11 = wy * wx;
    bool vy0 = (iy0 >= 0) && (iy0 < HH), vy1 = (iy1 >= 0) && (iy1 < HH);
    bool vx0 = (ix0 >= 0) && (ix0 < WW), vx1 = (ix1 >= 0) && (ix1 < WW);
    if (!(vy0 && vx0)) s.w00 = 0.f;
    if (!(vy0 && vx1)) s.w01 = 0.f;
    if (!(vy1 && vx0)) s.w10 = 0.f;
    if (!(vy1 && vx1)) s.w11 = 0.f;
    int cy0 = min(max(iy0, 0), HH - 1), cy1 = min(max(iy1, 0), HH - 1);
    int cx0 = min(max(ix0, 0), WW - 1), cx1 = min(max(ix1, 0), WW - 1);
    const unsigned short* q00 = xhib + xidx(cy0, si, cx0);
    const unsigned short* q01 = xhib + xidx(cy0, si, cx1);
    const unsigned short* q10 = xhib + xidx(cy1, si, cx0);
    const unsigned short* q11 = xhib + xidx(cy1, si, cx1);
    s.a00 = *(const uint4*)q00; s.a01 = *(const uint4*)q01;
    s.a10 = *(const uint4*)q10; s.a11 = *(const uint4*)q11;
    s.b00 = *(const uint4*)(q00 + 8); s.b01 = *(const uint4*)(q01 + 8);
    s.b10 = *(const uint4*)(q10 + 8); s.b11 = *(const uint4*)(q11 + 8);
    return s;
  };
  auto bodyB = [&](int kk, const BS& s) {
    // A-frag loads issued first: latency hides under blend + barrier.
    const short8* Ap = (const short8*)(wdA + (size_t)kk * 4096);
    short8 a0q0 = Ap[lane],        a1q0 = Ap[256 + lane];
    short8 a0q1 = Ap[64 + lane],   a1q1 = Ap[320 + lane];
    short8 a0q2 = Ap[128 + lane],  a1q2 = Ap[384 + lane];
    short8 a0q3 = Ap[192 + lane],  a1q3 = Ap[448 + lane];
    uint4 o0, o1;
    o0.x = bilin2(s.a00.x, s.a01.x, s.a10.x, s.a11.x, s.w00, s.w01, s.w10, s.w11);
    o0.y = bilin2(s.a00.y, s.a01.y, s.a10.y, s.a11.y, s.w00, s.w01, s.w10, s.w11);
    o0.z = bilin2(s.a00.z, s.a01.z, s.a10.z, s.a11.z, s.w00, s.w01, s.w10, s.w11);
    o0.w = bilin2(s.a00.w, s.a01.w, s.a10.w, s.a11.w, s.w00, s.w01, s.w10, s.w11);
    o1.x = bilin2(s.b00.x, s.b01.x, s.b10.x, s.b11.x, s.w00, s.w01, s.w10, s.w11);
    o1.y = bilin2(s.b00.y, s.b01.y, s.b10.y, s.b11.y, s.w00, s.w01, s.w10, s.w11);
    o1.z = bilin2(s.b00.z, s.b01.z, s.b10.z, s.b11.z, s.w00, s.w01, s.w10, s.w11);
    o1.w = bilin2(s.b00.w, s.b01.w, s.b10.w, s.b11.w, s.w00, s.w01, s.w10, s.w11);
    *(uint4*)stHi0 = o0;
    *(uint4*)stHi1 = o1;
    __syncthreads();
    short8 bv0 = *rdHi0, bv1 = *rdHi1;
    acc[0] = __builtin_amdgcn_mfma_f32_16x16x32_bf16(a0q0, bv0, acc[0], 0, 0, 0);
    acc[0] = __builtin_amdgcn_mfma_f32_16x16x32_bf16(a1q0, bv1, acc[0], 0, 0, 0);
    acc[1] = __builtin_amdgcn_mfma_f32_16x16x32_bf16(a0q1, bv0, acc[1], 0, 0, 0);
    acc[1] = __builtin_amdgcn_mfma_f32_16x16x32_bf16(a1q1, bv1, acc[1], 0, 0, 0);
    acc[2] = __builtin_amdgcn_mfma_f32_16x16x32_bf16(a0q2, bv0, acc[2], 0, 0, 0);
    acc[2] = __builtin_amdgcn_mfma_f32_16x16x32_bf16(a1q2, bv1, acc[2], 0, 0, 0);
    acc[3] = __builtin_amdgcn_mfma_f32_16x16x32_bf16(a0q3, bv0, acc[3], 0, 0, 0);
    acc[3] = __builtin_amdgcn_mfma_f32_16x16x32_bf16(a1q3, bv1, acc[3], 0, 0, 0);
    __syncthreads();
  };

  {
    BS sc = ldB(0);
#pragma unroll 1
    for (int kk = 0; kk < 8; kk++) {
      BS sn = ldB(kk + 1);    // issue next-iter loads (incl. offL LDS reads)
      bodyB(kk, sc);          // blend current (counted vmcnt), stage, MFMA
      sc = sn;
    }
    bodyB(8, sc);
  }

  // D: col = lane&15 (px in wave tile), row = (lane>>4)*4 + reg (cout in ct tile)
  int px = x0 + w * 16 + (lane & 15);
  int rowb = (lane >> 4) * 4;
  float* outb = out + (size_t)b * COUT * HWPIX + y * WW + px;
#pragma unroll
  for (int ct = 0; ct < 4; ct++)
#pragma unroll
    for (int rr = 0; rr < 4; rr++)
      outb[(size_t)(ct * 16 + rowb + rr) * HWPIX] = acc[ct][rr];
}

extern "C" void kernel_launch(void* const* d_in, const int* in_sizes, int n_in,
                              void* d_out, int out_size, void* d_ws, size_t ws_size,
                              hipStream_t stream) {
  const float* x  = (const float*)d_in[0];
  const float* wo = (const float*)d_in[1];
  const float* wd = (const float*)d_in[2];
  float* out = (float*)d_out;

  char* wsb = (char*)d_ws;
  unsigned short* xThi  = (unsigned short*)wsb;                         // 8,388,608 B
  unsigned short* xTlo  = (unsigned short*)(wsb + 8388608);             // 8,388,608 B
  unsigned short* wdA   = (unsigned short*)(wsb + 16777216);            // 73,728 B
  unsigned short* woAhi = (unsigned short*)(wsb + 16777216 + 73728);    // 36,864 B
  unsigned short* woAlo = (unsigned short*)(wsb + 16850944 + 36864);    // 36,864 B

  pre_kernel<<<dim3(4096 + 216), dim3(256), 0, stream>>>(x, wo, wd, xThi, xTlo, wdA, woAhi, woAlo);
  fused_dcn_kernel<<<dim3(BATCH * HWPIX / 64), dim3(256), 0, stream>>>(xThi, xTlo, woAhi, woAlo, wdA, out);
}

// Round 5
// 140.846 us; speedup vs baseline: 1.0205x; 1.0205x over previous
//
#include <hip/hip_runtime.h>

// DCNv2, fp32 in/out, all matmul-shaped work on bf16 MFMA.
// Round 5: direct-to-register B-fragments (R2 layout: lane = (px col, cin
// octet g)) + depth-1 software pipeline (R3): prefetch iteration kk+1's
// global loads before blending/consuming kk. No LDS staging of B at all,
// no per-kk barriers; only LDS = 4.5 KB offset tile with same-wave
// column ownership. Removes the ~455 KB/block LDS round-trip that bound
// R1/R3 at ~46us (LDS-pipe roofline).
//  - pre_kernel: x NCHW -> xT_hi/xT_lo bf16 NHWC (split-bf16) + weight A-frags
//  - fused_dcn_kernel: offset conv (im2col GEMM, 3-term split-bf16) ->
//    offsets in LDS -> bilinear sample into B-frags -> deform GEMM.
// ws: xThi 8388608 | xTlo 8388608 | wdA 73728 | woAhi 36864 | woAlo 36864

#define BATCH 4
#define CIN   64
#define COUT  64
#define HH    128
#define WW    128
#define HWPIX (HH*WW)

typedef __attribute__((ext_vector_type(8))) short short8;   // 8 bf16 (4 VGPRs)
typedef __attribute__((ext_vector_type(4))) float floatx4;  // MFMA C/D

__device__ __forceinline__ unsigned short f2bf(float f) {   // RNE f32->bf16
  unsigned int u = __float_as_uint(f);
  unsigned int r = u + 0x7fffu + ((u >> 16) & 1u);
  return (unsigned short)(r >> 16);
}
__device__ __forceinline__ float bf2f(unsigned short h) { return __uint_as_float(((unsigned int)h) << 16); }
__device__ __forceinline__ float lo16f(unsigned int u) { return __uint_as_float(u << 16); }
__device__ __forceinline__ float hi16f(unsigned int u) { return __uint_as_float(u & 0xffff0000u); }

__device__ __forceinline__ unsigned int bilin2(unsigned int u00, unsigned int u01,
                                               unsigned int u10, unsigned int u11,
                                               float w00, float w01, float w10, float w11) {
  float lo = w00 * lo16f(u00) + w01 * lo16f(u01) + w10 * lo16f(u10) + w11 * lo16f(u11);
  float hi = w00 * hi16f(u00) + w01 * hi16f(u01) + w10 * hi16f(u10) + w11 * hi16f(u11);
  return (unsigned int)f2bf(lo) | ((unsigned int)f2bf(hi) << 16);
}

// Fused preprocessing:
//  blocks [0,4096):  x fp32 NCHW -> xThi/xTlo bf16 [b][px][cin]
//  blocks [4096,4312): weight prep
//    wdA[kk][kc2][ct4][lane][j] bf16 (A-frag, 36864 elems);
//    woAhi/lo[kk][kc2][ct2][lane][j] bf16 (A-frag, M=32 rows, rows>=18 zero)
__global__ __launch_bounds__(256) void pre_kernel(const float* __restrict__ x,
                                                  const float* __restrict__ wo,
                                                  const float* __restrict__ wd,
                                                  unsigned short* __restrict__ xThi,
                                                  unsigned short* __restrict__ xTlo,
                                                  unsigned short* __restrict__ wdA,
                                                  unsigned short* __restrict__ woAhi,
                                                  unsigned short* __restrict__ woAlo) {
  int tid = threadIdx.x;
  if (blockIdx.x < 4096) {
    __shared__ float tile[32][33];   // [c_local][p_local]
    int t = blockIdx.x;
    int b = t >> 10, rem = t & 1023;
    int c0 = (rem >> 9) * 32, p0 = (rem & 511) * 32;
    int tx = tid & 31, ty = tid >> 5;      // (32,8)
    const float* xb = x + (size_t)b * CIN * HWPIX;
    size_t boff = (size_t)b * HWPIX * CIN;
#pragma unroll
    for (int i = 0; i < 4; i++)
      tile[ty + i * 8][tx] = xb[(size_t)(c0 + ty + i * 8) * HWPIX + p0 + tx];
    __syncthreads();
#pragma unroll
    for (int i = 0; i < 2; i++) {
      int tt = tid + i * 256;       // 0..511 = 32 rows * 16 cin-pairs
      int row = tt >> 4;
      int cp = tt & 15;
      float v0 = tile[cp * 2][row], v1 = tile[cp * 2 + 1][row];
      unsigned short h0 = f2bf(v0), h1 = f2bf(v1);
      unsigned short l0 = f2bf(v0 - bf2f(h0)), l1 = f2bf(v1 - bf2f(h1));
      size_t o = boff + (size_t)(p0 + row) * CIN + c0 + cp * 2;
      *(ushort2*)&xThi[o] = make_ushort2(h0, h1);
      *(ushort2*)&xTlo[o] = make_ushort2(l0, l1);
    }
  } else {
    int t = (blockIdx.x - 4096) * 256 + tid;
    if (t < 36864) {
      int j = t & 7, lane = (t >> 3) & 63, ct = (t >> 9) & 3, kc = (t >> 11) & 1, kk = t >> 12;
      int cout = ct * 16 + (lane & 15);
      int cin  = kc * 32 + (lane >> 4) * 8 + j;
      wdA[t] = f2bf(wd[(size_t)(cout * CIN + cin) * 9 + kk]);
    }
    int t2 = t - 36864;
    if (t2 >= 0 && t2 < 18432) {
      int j = t2 & 7, lane = (t2 >> 3) & 63, ct = (t2 >> 9) & 1, kc = (t2 >> 10) & 1, kk = t2 >> 11;
      int cout = ct * 16 + (lane & 15);          // conv channel 0..31 (valid < 18)
      int cin  = kc * 32 + (lane >> 4) * 8 + j;
      float v = (cout < 18) ? wo[(size_t)(cout * CIN + cin) * 9 + kk] : 0.f;
      unsigned short h = f2bf(v);
      woAhi[t2] = h;
      woAlo[t2] = f2bf(v - bf2f(h));
    }
  }
}

// Fused offset-conv + deform GEMM: direct-frag, barrier-free, pipelined.
// Block: 64 px tile (b, y, x0..x0+63), 4 waves; wave w owns px
// [x0+16w, x0+16w+16). Lane l: col = l&15 (px), g = l>>4 (cin octets
// g*8..+8 and 32+g*8..+8) — exactly the mfma_16x16x32 B-frag layout, so
// loaded/sampled values feed MFMA straight from registers.
__global__ __launch_bounds__(256) void fused_dcn_kernel(const unsigned short* __restrict__ xThi,
                                                        const unsigned short* __restrict__ xTlo,
                                                        const unsigned short* __restrict__ woAhi,
                                                        const unsigned short* __restrict__ woAlo,
                                                        const unsigned short* __restrict__ wdA,
                                                        float* __restrict__ out) {
  __shared__ float offL[18 * 64];          // 4.5 KB; [chan][px_local], per-wave cols

  int tid = threadIdx.x;
  int hw = blockIdx.x;
  int bid = (hw & 7) * 128 + (hw >> 3);    // XCD-contiguous y bands
  int b = bid >> 8, r = bid & 255, y = r >> 1, x0 = (r & 1) << 6;

  int lane = tid & 63, w = tid >> 6;
  int col = lane & 15, g = lane >> 4;
  int wcol = w * 16 + col;                 // px local to block
  int px = x0 + wcol;                      // this lane's pixel
  int coff = g * 8;                        // first cin octet; second at +32

  const unsigned short* xhib = xThi + (size_t)b * HWPIX * CIN;
  const unsigned short* xlob = xTlo + (size_t)b * HWPIX * CIN;

  // ================= Phase A: offset conv (pipelined, direct-frag) ==========
  floatx4 oacc[2];
  oacc[0] = (floatx4){0.f, 0.f, 0.f, 0.f};
  oacc[1] = (floatx4){0.f, 0.f, 0.f, 0.f};

  auto ldA = [&](int kk, uint4& h0, uint4& h1, uint4& l0, uint4& l1) {
    int ys = y - 1 + kk / 3;
    int xs = px - 1 + kk % 3;
    bool valid = (ys >= 0) && (ys < HH) && (xs >= 0) && (xs < WW);
    h0 = (uint4){0, 0, 0, 0}; h1 = h0; l0 = h0; l1 = h0;
    if (valid) {
      const unsigned short* ph = xhib + (size_t)(ys * WW + xs) * CIN + coff;
      const unsigned short* pl = xlob + (size_t)(ys * WW + xs) * CIN + coff;
      h0 = *(const uint4*)ph; h1 = *(const uint4*)(ph + 32);
      l0 = *(const uint4*)pl; l1 = *(const uint4*)(pl + 32);
    }
  };
  auto bodyA = [&](int kk, const uint4& h0, const uint4& h1, const uint4& l0, const uint4& l1) {
    const short8* Ah = (const short8*)(woAhi + (size_t)kk * 2048);
    const short8* Al = (const short8*)(woAlo + (size_t)kk * 2048);
    short8 ah0a = Ah[lane],       ah1a = Ah[128 + lane];
    short8 al0a = Al[lane],       al1a = Al[128 + lane];
    short8 ah0b = Ah[64 + lane],  ah1b = Ah[192 + lane];
    short8 al0b = Al[64 + lane],  al1b = Al[192 + lane];
    short8 bh0 = *(short8*)&h0, bh1 = *(short8*)&h1;
    short8 bl0 = *(short8*)&l0, bl1 = *(short8*)&l1;
    oacc[0] = __builtin_amdgcn_mfma_f32_16x16x32_bf16(ah0a, bh0, oacc[0], 0, 0, 0);
    oacc[0] = __builtin_amdgcn_mfma_f32_16x16x32_bf16(ah0a, bl0, oacc[0], 0, 0, 0);
    oacc[0] = __builtin_amdgcn_mfma_f32_16x16x32_bf16(al0a, bh0, oacc[0], 0, 0, 0);
    oacc[0] = __builtin_amdgcn_mfma_f32_16x16x32_bf16(ah1a, bh1, oacc[0], 0, 0, 0);
    oacc[0] = __builtin_amdgcn_mfma_f32_16x16x32_bf16(ah1a, bl1, oacc[0], 0, 0, 0);
    oacc[0] = __builtin_amdgcn_mfma_f32_16x16x32_bf16(al1a, bh1, oacc[0], 0, 0, 0);
    oacc[1] = __builtin_amdgcn_mfma_f32_16x16x32_bf16(ah0b, bh0, oacc[1], 0, 0, 0);
    oacc[1] = __builtin_amdgcn_mfma_f32_16x16x32_bf16(ah0b, bl0, oacc[1], 0, 0, 0);
    oacc[1] = __builtin_amdgcn_mfma_f32_16x16x32_bf16(al0b, bh0, oacc[1], 0, 0, 0);
    oacc[1] = __builtin_amdgcn_mfma_f32_16x16x32_bf16(ah1b, bh1, oacc[1], 0, 0, 0);
    oacc[1] = __builtin_amdgcn_mfma_f32_16x16x32_bf16(ah1b, bl1, oacc[1], 0, 0, 0);
    oacc[1] = __builtin_amdgcn_mfma_f32_16x16x32_bf16(al1b, bh1, oacc[1], 0, 0, 0);
  };

  {
    uint4 h0c, h1c, l0c, l1c;
    ldA(0, h0c, h1c, l0c, l1c);
#pragma unroll 1
    for (int kk = 0; kk < 8; kk++) {
      uint4 h0n, h1n, l0n, l1n;
      ldA(kk + 1, h0n, h1n, l0n, l1n);      // issue next-iter loads
      bodyA(kk, h0c, h1c, l0c, l1c);        // consume current (counted vmcnt)
      h0c = h0n; h1c = h1n; l0c = l0n; l1c = l1n;
    }
    bodyA(8, h0c, h1c, l0c, l1c);
  }

  // Scatter offsets to LDS. D layout: col=lane&15 (px), row=(lane>>4)*4+rr.
  // Wave w writes only columns [16w,16w+16) and reads only those below ->
  // same-wave ordering, no __syncthreads needed.
  {
    int rowb = g * 4;
#pragma unroll
    for (int ct = 0; ct < 2; ct++)
#pragma unroll
      for (int rr = 0; rr < 4; rr++) {
        int row = ct * 16 + rowb + rr;
        if (row < 18) offL[row * 64 + wcol] = oacc[ct][rr];
      }
  }

  // ================= Phase B: deform sample + GEMM (pipelined, direct-frag) =
  floatx4 acc[4];
#pragma unroll
  for (int ct = 0; ct < 4; ct++) acc[ct] = (floatx4){0.f, 0.f, 0.f, 0.f};

  struct BS {
    float w00, w01, w10, w11;
    uint4 a00, a01, a10, a11, b00, b01, b10, b11;
  };
  auto ldB = [&](int kk) -> BS {
    BS s;
    float dy = offL[(2 * kk) * 64 + wcol];
    float dx = offL[(2 * kk + 1) * 64 + wcol];
    float ys = (float)(y - 1 + kk / 3) + dy;
    float xs = (float)(px - 1 + kk % 3) + dx;
    float y0f = floorf(ys), x0f = floorf(xs);
    float wy = ys - y0f, wx = xs - x0f;
    int iy0 = (int)y0f, ix0 = (int)x0f;
    int iy1 = iy0 + 1, ix1 = ix0 + 1;
    s.w00 = (1.f - wy) * (1.f - wx); s.w01 = (1.f - wy) * wx;
    s.w10 = wy * (1.f - wx);         s.w11 = wy * wx;
    bool vy0 = (iy0 >= 0) && (iy0 < HH), vy1 = (iy1 >= 0) && (iy1 < HH);
    bool vx0 = (ix0 >= 0) && (ix0 < WW), vx1 = (ix1 >= 0) && (ix1 < WW);
    if (!(vy0 && vx0)) s.w00 = 0.f;
    if (!(vy0 && vx1)) s.w01 = 0.f;
    if (!(vy1 && vx0)) s.w10 = 0.f;
    if (!(vy1 && vx1)) s.w11 = 0.f;
    int cy0 = min(max(iy0, 0), HH - 1), cy1 = min(max(iy1, 0), HH - 1);
    int cx0 = min(max(ix0, 0), WW - 1), cx1 = min(max(ix1, 0), WW - 1);
    const unsigned short* q00 = xhib + (size_t)(cy0 * WW + cx0) * CIN + coff;
    const unsigned short* q01 = xhib + (size_t)(cy0 * WW + cx1) * CIN + coff;
    const unsigned short* q10 = xhib + (size_t)(cy1 * WW + cx0) * CIN + coff;
    const unsigned short* q11 = xhib + (size_t)(cy1 * WW + cx1) * CIN + coff;
    s.a00 = *(const uint4*)q00; s.a01 = *(const uint4*)q01;
    s.a10 = *(const uint4*)q10; s.a11 = *(const uint4*)q11;
    s.b00 = *(const uint4*)(q00 + 32); s.b01 = *(const uint4*)(q01 + 32);
    s.b10 = *(const uint4*)(q10 + 32); s.b11 = *(const uint4*)(q11 + 32);
    return s;
  };
  auto bodyB = [&](int kk, const BS& s) {
    const short8* Ap = (const short8*)(wdA + (size_t)kk * 4096);
    short8 a0q0 = Ap[lane],        a1q0 = Ap[256 + lane];
    short8 a0q1 = Ap[64 + lane],   a1q1 = Ap[320 + lane];
    short8 a0q2 = Ap[128 + lane],  a1q2 = Ap[384 + lane];
    short8 a0q3 = Ap[192 + lane],  a1q3 = Ap[448 + lane];
    uint4 o0, o1;
    o0.x = bilin2(s.a00.x, s.a01.x, s.a10.x, s.a11.x, s.w00, s.w01, s.w10, s.w11);
    o0.y = bilin2(s.a00.y, s.a01.y, s.a10.y, s.a11.y, s.w00, s.w01, s.w10, s.w11);
    o0.z = bilin2(s.a00.z, s.a01.z, s.a10.z, s.a11.z, s.w00, s.w01, s.w10, s.w11);
    o0.w = bilin2(s.a00.w, s.a01.w, s.a10.w, s.a11.w, s.w00, s.w01, s.w10, s.w11);
    o1.x = bilin2(s.b00.x, s.b01.x, s.b10.x, s.b11.x, s.w00, s.w01, s.w10, s.w11);
    o1.y = bilin2(s.b00.y, s.b01.y, s.b10.y, s.b11.y, s.w00, s.w01, s.w10, s.w11);
    o1.z = bilin2(s.b00.z, s.b01.z, s.b10.z, s.b11.z, s.w00, s.w01, s.w10, s.w11);
    o1.w = bilin2(s.b00.w, s.b01.w, s.b10.w, s.b11.w, s.w00, s.w01, s.w10, s.w11);
    short8 bv0 = *(short8*)&o0, bv1 = *(short8*)&o1;
    acc[0] = __builtin_amdgcn_mfma_f32_16x16x32_bf16(a0q0, bv0, acc[0], 0, 0, 0);
    acc[0] = __builtin_amdgcn_mfma_f32_16x16x32_bf16(a1q0, bv1, acc[0], 0, 0, 0);
    acc[1] = __builtin_amdgcn_mfma_f32_16x16x32_bf16(a0q1, bv0, acc[1], 0, 0, 0);
    acc[1] = __builtin_amdgcn_mfma_f32_16x16x32_bf16(a1q1, bv1, acc[1], 0, 0, 0);
    acc[2] = __builtin_amdgcn_mfma_f32_16x16x32_bf16(a0q2, bv0, acc[2], 0, 0, 0);
    acc[2] = __builtin_amdgcn_mfma_f32_16x16x32_bf16(a1q2, bv1, acc[2], 0, 0, 0);
    acc[3] = __builtin_amdgcn_mfma_f32_16x16x32_bf16(a0q3, bv0, acc[3], 0, 0, 0);
    acc[3] = __builtin_amdgcn_mfma_f32_16x16x32_bf16(a1q3, bv1, acc[3], 0, 0, 0);
  };

  {
    BS sc = ldB(0);
#pragma unroll 1
    for (int kk = 0; kk < 8; kk++) {
      BS sn = ldB(kk + 1);    // issue next-iter loads (incl. offL reads)
      bodyB(kk, sc);          // blend current (counted vmcnt) + MFMA
      sc = sn;
    }
    bodyB(8, sc);
  }

  // D: col = lane&15 (px in wave tile), row = (lane>>4)*4 + reg (cout in ct tile)
  int rowb = g * 4;
  float* outb = out + (size_t)b * COUT * HWPIX + y * WW + px;
#pragma unroll
  for (int ct = 0; ct < 4; ct++)
#pragma unroll
    for (int rr = 0; rr < 4; rr++)
      outb[(size_t)(ct * 16 + rowb + rr) * HWPIX] = acc[ct][rr];
}

extern "C" void kernel_launch(void* const* d_in, const int* in_sizes, int n_in,
                              void* d_out, int out_size, void* d_ws, size_t ws_size,
                              hipStream_t stream) {
  const float* x  = (const float*)d_in[0];
  const float* wo = (const float*)d_in[1];
  const float* wd = (const float*)d_in[2];
  float* out = (float*)d_out;

  char* wsb = (char*)d_ws;
  unsigned short* xThi  = (unsigned short*)wsb;                         // 8,388,608 B
  unsigned short* xTlo  = (unsigned short*)(wsb + 8388608);             // 8,388,608 B
  unsigned short* wdA   = (unsigned short*)(wsb + 16777216);            // 73,728 B
  unsigned short* woAhi = (unsigned short*)(wsb + 16777216 + 73728);    // 36,864 B
  unsigned short* woAlo = (unsigned short*)(wsb + 16850944 + 36864);    // 36,864 B

  pre_kernel<<<dim3(4096 + 216), dim3(256), 0, stream>>>(x, wo, wd, xThi, xTlo, wdA, woAhi, woAlo);
  fused_dcn_kernel<<<dim3(BATCH * HWPIX / 64), dim3(256), 0, stream>>>(xThi, xTlo, woAhi, woAlo, wdA, out);
}

// Round 7
// 125.461 us; speedup vs baseline: 1.1456x; 1.1226x over previous
//
#include <hip/hip_runtime.h>

// DCNv2, fp32 in/out, all matmul-shaped work on bf16 MFMA.
// Round 7 = Round 6 resubmit (container infra failure, no data).
// Split-cin wave parallelism. Fused kernel: 2048 blocks x 256 thr,
// 4 waves = (wg = cin-half) x (wv = px-half), 32 px per block.
//  - Phase A (offset conv, im2col GEMM, 3-term split-bf16): duplicated per
//    wg group (bitwise-identical) -> offsets in LDS, no reduction needed.
//  - Phase B (bilinear sample + deform GEMM): each wave handles 32 cin ->
//    per-wave chain halves, wave count doubles (8192 waves = 8/SIMD).
//    Final cross-half acc reduction through 8KB LDS.
// Staging: one 8KB LDS buffer, XOR swizzle bits[8:10]->[4:6] (balanced).
// ws: xThi 8388608 | xTlo 8388608 | wdA 73728 | woAhi 36864 | woAlo 36864

#define BATCH 4
#define CIN   64
#define COUT  64
#define HH    128
#define WW    128
#define HWPIX (HH*WW)

typedef __attribute__((ext_vector_type(8))) short short8;   // 8 bf16 (4 VGPRs)
typedef __attribute__((ext_vector_type(4))) float floatx4;  // MFMA C/D

__device__ __forceinline__ unsigned short f2bf(float f) {   // RNE f32->bf16
  unsigned int u = __float_as_uint(f);
  unsigned int r = u + 0x7fffu + ((u >> 16) & 1u);
  return (unsigned short)(r >> 16);
}
__device__ __forceinline__ float bf2f(unsigned short h) { return __uint_as_float(((unsigned int)h) << 16); }
__device__ __forceinline__ float lo16f(unsigned int u) { return __uint_as_float(u << 16); }
__device__ __forceinline__ float hi16f(unsigned int u) { return __uint_as_float(u & 0xffff0000u); }

__device__ __forceinline__ unsigned int bilin2(unsigned int u00, unsigned int u01,
                                               unsigned int u10, unsigned int u11,
                                               float w00, float w01, float w10, float w11) {
  float lo = w00 * lo16f(u00) + w01 * lo16f(u01) + w10 * lo16f(u10) + w11 * lo16f(u11);
  float hi = w00 * hi16f(u00) + w01 * hi16f(u01) + w10 * hi16f(u10) + w11 * hi16f(u11);
  return (unsigned int)f2bf(lo) | ((unsigned int)f2bf(hi) << 16);
}

// LDS byte swizzle: fold bits 8-10 into 4-6 (bijective involution).
__device__ __forceinline__ int swzB(int a) { return a ^ (((a >> 8) & 7) << 4); }

// Fused preprocessing (unchanged from R1):
//  blocks [0,4096):  x fp32 NCHW -> xThi/xTlo bf16 [b][px][cin]
//  blocks [4096,4312): weight prep
//    wdA[kk][kc2][ct4][lane][j] bf16; woAhi/lo[kk][kc2][ct2][lane][j] bf16
__global__ __launch_bounds__(256) void pre_kernel(const float* __restrict__ x,
                                                  const float* __restrict__ wo,
                                                  const float* __restrict__ wd,
                                                  unsigned short* __restrict__ xThi,
                                                  unsigned short* __restrict__ xTlo,
                                                  unsigned short* __restrict__ wdA,
                                                  unsigned short* __restrict__ woAhi,
                                                  unsigned short* __restrict__ woAlo) {
  int tid = threadIdx.x;
  if (blockIdx.x < 4096) {
    __shared__ float tile[32][33];   // [c_local][p_local]
    int t = blockIdx.x;
    int b = t >> 10, rem = t & 1023;
    int c0 = (rem >> 9) * 32, p0 = (rem & 511) * 32;
    int tx = tid & 31, ty = tid >> 5;      // (32,8)
    const float* xb = x + (size_t)b * CIN * HWPIX;
    size_t boff = (size_t)b * HWPIX * CIN;
#pragma unroll
    for (int i = 0; i < 4; i++)
      tile[ty + i * 8][tx] = xb[(size_t)(c0 + ty + i * 8) * HWPIX + p0 + tx];
    __syncthreads();
#pragma unroll
    for (int i = 0; i < 2; i++) {
      int tt = tid + i * 256;       // 0..511 = 32 rows * 16 cin-pairs
      int row = tt >> 4;
      int cp = tt & 15;
      float v0 = tile[cp * 2][row], v1 = tile[cp * 2 + 1][row];
      unsigned short h0 = f2bf(v0), h1 = f2bf(v1);
      unsigned short l0 = f2bf(v0 - bf2f(h0)), l1 = f2bf(v1 - bf2f(h1));
      size_t o = boff + (size_t)(p0 + row) * CIN + c0 + cp * 2;
      *(ushort2*)&xThi[o] = make_ushort2(h0, h1);
      *(ushort2*)&xTlo[o] = make_ushort2(l0, l1);
    }
  } else {
    int t = (blockIdx.x - 4096) * 256 + tid;
    if (t < 36864) {
      int j = t & 7, lane = (t >> 3) & 63, ct = (t >> 9) & 3, kc = (t >> 11) & 1, kk = t >> 12;
      int cout = ct * 16 + (lane & 15);
      int cin  = kc * 32 + (lane >> 4) * 8 + j;
      wdA[t] = f2bf(wd[(size_t)(cout * CIN + cin) * 9 + kk]);
    }
    int t2 = t - 36864;
    if (t2 >= 0 && t2 < 18432) {
      int j = t2 & 7, lane = (t2 >> 3) & 63, ct = (t2 >> 9) & 1, kc = (t2 >> 10) & 1, kk = t2 >> 11;
      int cout = ct * 16 + (lane & 15);          // conv channel 0..31 (valid < 18)
      int cin  = kc * 32 + (lane >> 4) * 8 + j;
      float v = (cout < 18) ? wo[(size_t)(cout * CIN + cin) * 9 + kk] : 0.f;
      unsigned short h = f2bf(v);
      woAhi[t2] = h;
      woAlo[t2] = f2bf(v - bf2f(h));
    }
  }
}

// Fused offset-conv + deform GEMM, split-cin.
// Block: 32 px (b, y, x0..x0+31), 256 thr = 4 waves: wave w: wv=w&1 (px half
// [x0+16wv, +16)), wg=w>>1 (cin half kc=wg).
// Staging view: p1 = tid>>3 (px 0..31), o = tid&7 (8-ch octet / hi-lo slice).
__global__ __launch_bounds__(256) void fused_dcn_kernel(const unsigned short* __restrict__ xThi,
                                                        const unsigned short* __restrict__ xTlo,
                                                        const unsigned short* __restrict__ woAhi,
                                                        const unsigned short* __restrict__ woAlo,
                                                        const unsigned short* __restrict__ wdA,
                                                        float* __restrict__ out) {
  __shared__ unsigned short sB[4096];      // 8 KB staging / reduction buffer
  __shared__ float offL[18 * 32];          // 2.25 KB offsets [chan][px_local]
  char* sBc = (char*)sB;

  int tid = threadIdx.x;
  int hw = blockIdx.x;
  int bid = (hw & 7) * 256 + (hw >> 3);    // XCD-contiguous y bands (2048%8==0)
  int b = bid >> 9, r = bid & 511, y = r >> 2, x0 = (r & 3) << 5;

  int lane = tid & 63, w = tid >> 6;
  int wv = w & 1, wg = w >> 1;
  int p1 = tid >> 3, o = tid & 7;
  int xp = x0 + p1;                        // staging pixel

  const unsigned short* xhib = xThi + (size_t)b * HWPIX * CIN;
  const unsigned short* xlob = xTlo + (size_t)b * HWPIX * CIN;

  // ================= Phase A: offset conv (duplicated per wg) ==============
  floatx4 oacc[2];
  oacc[0] = (floatx4){0.f, 0.f, 0.f, 0.f};
  oacc[1] = (floatx4){0.f, 0.f, 0.f, 0.f};

  // staging address (bytes, pre-swizzle): [hi/lo 4KB][wq][kcd][qb*512][iq*16]
  int siA = o & 3;
  int abase = ((o < 4) ? 0 : 4096) +
              (((p1 >> 4) * 2 + (siA >> 1)) << 10) + ((siA & 1) << 9) + ((p1 & 15) << 4);

#pragma unroll 1
  for (int kk = 0; kk < 9; kk++) {
    int ys = y - 1 + kk / 3;
    int xs = xp - 1 + kk % 3;
    bool valid = (ys >= 0) && (ys < HH) && (xs >= 0) && (xs < WW);
    uint4 v0 = {0, 0, 0, 0}, v1 = {0, 0, 0, 0};
    if (valid) {
      const unsigned short* arr = (o < 4) ? xhib : xlob;
      const unsigned short* ph = arr + (size_t)(ys * WW + xs) * CIN + siA * 16;
      v0 = *(const uint4*)ph; v1 = *(const uint4*)(ph + 8);
    }
    *(uint4*)(sBc + swzB(abase)) = v0;
    *(uint4*)(sBc + swzB(abase + 256)) = v1;
    __syncthreads();
    // every wave: full-cin 3-term offset GEMM for its px half
    const short8* Ah = (const short8*)(woAhi + (size_t)kk * 2048);
    const short8* Al = (const short8*)(woAlo + (size_t)kk * 2048);
    short8 bh0 = *(const short8*)(sBc + swzB(wv * 2048 + lane * 16));
    short8 bh1 = *(const short8*)(sBc + swzB(wv * 2048 + 1024 + lane * 16));
    short8 bl0 = *(const short8*)(sBc + swzB(4096 + wv * 2048 + lane * 16));
    short8 bl1 = *(const short8*)(sBc + swzB(4096 + wv * 2048 + 1024 + lane * 16));
#pragma unroll
    for (int ct = 0; ct < 2; ct++) {
      short8 ah0 = Ah[ct * 64 + lane], ah1 = Ah[128 + ct * 64 + lane];
      short8 al0 = Al[ct * 64 + lane], al1 = Al[128 + ct * 64 + lane];
      oacc[ct] = __builtin_amdgcn_mfma_f32_16x16x32_bf16(ah0, bh0, oacc[ct], 0, 0, 0);
      oacc[ct] = __builtin_amdgcn_mfma_f32_16x16x32_bf16(ah0, bl0, oacc[ct], 0, 0, 0);
      oacc[ct] = __builtin_amdgcn_mfma_f32_16x16x32_bf16(al0, bh0, oacc[ct], 0, 0, 0);
      oacc[ct] = __builtin_amdgcn_mfma_f32_16x16x32_bf16(ah1, bh1, oacc[ct], 0, 0, 0);
      oacc[ct] = __builtin_amdgcn_mfma_f32_16x16x32_bf16(ah1, bl1, oacc[ct], 0, 0, 0);
      oacc[ct] = __builtin_amdgcn_mfma_f32_16x16x32_bf16(al1, bh1, oacc[ct], 0, 0, 0);
    }
    __syncthreads();
  }

  // offL scatter: wg0 only (wg1 computed identical values), then barrier.
  if (wg == 0) {
    int wcol = wv * 16 + (lane & 15);
    int rowb = (lane >> 4) * 4;
#pragma unroll
    for (int ct = 0; ct < 2; ct++)
#pragma unroll
      for (int rr = 0; rr < 4; rr++) {
        int row = ct * 16 + rowb + rr;
        if (row < 18) offL[row * 32 + wcol] = oacc[ct][rr];
      }
  }
  __syncthreads();

  // ================= Phase B: sample + deform GEMM (split-cin) =============
  floatx4 acc[4];
#pragma unroll
  for (int ct = 0; ct < 4; ct++) acc[ct] = (floatx4){0.f, 0.f, 0.f, 0.f};

  // staging address (bytes, pre-swizzle): [wq][kc=o>>2][g=o&3][iq]
  int bbase = (((p1 >> 4) * 2 + (o >> 2)) << 10) + ((o & 3) << 8) + ((p1 & 15) << 4);
  int rdB = wv * 2048 + wg * 1024 + lane * 16;

#pragma unroll 1
  for (int kk = 0; kk < 9; kk++) {
    // ---- stage: sample 8 ch (octet o) for px p1 ----
    {
      float dy = offL[(2 * kk) * 32 + p1];
      float dx = offL[(2 * kk + 1) * 32 + p1];
      float ys = (float)(y - 1 + kk / 3) + dy;
      float xs = (float)(xp - 1 + kk % 3) + dx;
      float y0f = floorf(ys), x0f = floorf(xs);
      float wy = ys - y0f, wx = xs - x0f;
      int iy0 = (int)y0f, ix0 = (int)x0f;
      int iy1 = iy0 + 1, ix1 = ix0 + 1;
      float w00 = (1.f - wy) * (1.f - wx), w01 = (1.f - wy) * wx;
      float w10 = wy * (1.f - wx), w11 = wy * wx;
      bool vy0 = (iy0 >= 0) && (iy0 < HH), vy1 = (iy1 >= 0) && (iy1 < HH);
      bool vx0 = (ix0 >= 0) && (ix0 < WW), vx1 = (ix1 >= 0) && (ix1 < WW);
      if (!(vy0 && vx0)) w00 = 0.f;
      if (!(vy0 && vx1)) w01 = 0.f;
      if (!(vy1 && vx0)) w10 = 0.f;
      if (!(vy1 && vx1)) w11 = 0.f;
      int cy0 = min(max(iy0, 0), HH - 1), cy1 = min(max(iy1, 0), HH - 1);
      int cx0 = min(max(ix0, 0), WW - 1), cx1 = min(max(ix1, 0), WW - 1);
      const unsigned short* q00 = xhib + (size_t)(cy0 * WW + cx0) * CIN + o * 8;
      const unsigned short* q01 = xhib + (size_t)(cy0 * WW + cx1) * CIN + o * 8;
      const unsigned short* q10 = xhib + (size_t)(cy1 * WW + cx0) * CIN + o * 8;
      const unsigned short* q11 = xhib + (size_t)(cy1 * WW + cx1) * CIN + o * 8;
      uint4 a00 = *(const uint4*)q00, a01 = *(const uint4*)q01;
      uint4 a10 = *(const uint4*)q10, a11 = *(const uint4*)q11;
      uint4 o0;
      o0.x = bilin2(a00.x, a01.x, a10.x, a11.x, w00, w01, w10, w11);
      o0.y = bilin2(a00.y, a01.y, a10.y, a11.y, w00, w01, w10, w11);
      o0.z = bilin2(a00.z, a01.z, a10.z, a11.z, w00, w01, w10, w11);
      o0.w = bilin2(a00.w, a01.w, a10.w, a11.w, w00, w01, w10, w11);
      *(uint4*)(sBc + swzB(bbase)) = o0;
    }
    __syncthreads();
    // ---- MFMA: this wave's cin half ----
    {
      short8 bv = *(const short8*)(sBc + swzB(rdB));
      const unsigned short* Ap = wdA + (size_t)kk * 4096 + wg * 2048;
#pragma unroll
      for (int ct = 0; ct < 4; ct++) {
        short8 a = *(const short8*)(Ap + ct * 512 + lane * 8);
        acc[ct] = __builtin_amdgcn_mfma_f32_16x16x32_bf16(a, bv, acc[ct], 0, 0, 0);
      }
    }
    __syncthreads();
  }

  // ================= cross-half reduction + output =================
  float* rf = (float*)sB;    // 2048 floats, layout [ct][wv][lane][4]
  if (wg == 1) {
#pragma unroll
    for (int ct = 0; ct < 4; ct++)
      *(floatx4*)&rf[(((ct * 2) + wv) * 64 + lane) * 4] = acc[ct];
  }
  __syncthreads();
  if (wg == 0) {
    int px = x0 + wv * 16 + (lane & 15);
    int rowb = (lane >> 4) * 4;
    float* outb = out + (size_t)b * COUT * HWPIX + y * WW + px;
#pragma unroll
    for (int ct = 0; ct < 4; ct++) {
      floatx4 other = *(floatx4*)&rf[(((ct * 2) + wv) * 64 + lane) * 4];
#pragma unroll
      for (int rr = 0; rr < 4; rr++)
        outb[(size_t)(ct * 16 + rowb + rr) * HWPIX] = acc[ct][rr] + other[rr];
    }
  }
}

extern "C" void kernel_launch(void* const* d_in, const int* in_sizes, int n_in,
                              void* d_out, int out_size, void* d_ws, size_t ws_size,
                              hipStream_t stream) {
  const float* x  = (const float*)d_in[0];
  const float* wo = (const float*)d_in[1];
  const float* wd = (const float*)d_in[2];
  float* out = (float*)d_out;

  char* wsb = (char*)d_ws;
  unsigned short* xThi  = (unsigned short*)wsb;                         // 8,388,608 B
  unsigned short* xTlo  = (unsigned short*)(wsb + 8388608);             // 8,388,608 B
  unsigned short* wdA   = (unsigned short*)(wsb + 16777216);            // 73,728 B
  unsigned short* woAhi = (unsigned short*)(wsb + 16777216 + 73728);    // 36,864 B
  unsigned short* woAlo = (unsigned short*)(wsb + 16850944 + 36864);    // 36,864 B

  pre_kernel<<<dim3(4096 + 216), dim3(256), 0, stream>>>(x, wo, wd, xThi, xTlo, wdA, woAhi, woAlo);
  fused_dcn_kernel<<<dim3(2048), dim3(256), 0, stream>>>(xThi, xTlo, woAhi, woAlo, wdA, out);
}

// Round 8
// 115.884 us; speedup vs baseline: 1.2403x; 1.0826x over previous
//
#include <hip/hip_runtime.h>

// DCNv2, fp32 in/out, all matmul-shaped work on bf16 MFMA.
// Round 8: R3 base (best: 46.1us fused) + two critical-path cuts:
//  (1) v_cvt_pk_bf16_f32 replaces manual f2bf-pair+pack in the bilinear
//      blend (RNE == f2bf, bit-identical; ~9 -> 1 op per 2 channels).
//  (2) double-buffered LDS staging, ONE barrier per kk (was 2): iter =
//      {issue gathers(kk+1) -> MFMA(kk, cur buf) -> blend/stage(kk+1, next
//      buf) -> barrier}. Gather latency hides under MFMA + A-frag loads.
//  - pre_kernel: x NCHW -> xT_hi/xT_lo bf16 NHWC (split-bf16) + weight A-frags
//  - fused_dcn_kernel: offset conv (im2col GEMM, 3-term split-bf16) ->
//    offsets in LDS -> bilinear sample -> LDS B-frags -> deform GEMM.
// ws: xThi 8388608 | xTlo 8388608 | wdA 73728 | woAhi 36864 | woAlo 36864

#define BATCH 4
#define CIN   64
#define COUT  64
#define HH    128
#define WW    128
#define HWPIX (HH*WW)

typedef __attribute__((ext_vector_type(8))) short short8;   // 8 bf16 (4 VGPRs)
typedef __attribute__((ext_vector_type(4))) float floatx4;  // MFMA C/D

__device__ __forceinline__ unsigned short f2bf(float f) {   // RNE f32->bf16
  unsigned int u = __float_as_uint(f);
  unsigned int r = u + 0x7fffu + ((u >> 16) & 1u);
  return (unsigned short)(r >> 16);
}
__device__ __forceinline__ float bf2f(unsigned short h) { return __uint_as_float(((unsigned int)h) << 16); }
__device__ __forceinline__ float lo16f(unsigned int u) { return __uint_as_float(u << 16); }
__device__ __forceinline__ float hi16f(unsigned int u) { return __uint_as_float(u & 0xffff0000u); }

// 2-channel bilinear blend; pack via HW RNE convert (== f2bf pair, 1 instr).
__device__ __forceinline__ unsigned int bilin2(unsigned int u00, unsigned int u01,
                                               unsigned int u10, unsigned int u11,
                                               float w00, float w01, float w10, float w11) {
  float lo = w00 * lo16f(u00) + w01 * lo16f(u01) + w10 * lo16f(u10) + w11 * lo16f(u11);
  float hi = w00 * hi16f(u00) + w01 * hi16f(u01) + w10 * hi16f(u10) + w11 * hi16f(u11);
  unsigned int r;
  asm("v_cvt_pk_bf16_f32 %0, %1, %2" : "=v"(r) : "v"(lo), "v"(hi));
  return r;
}

// LDS byte-offset swizzle: fold bits 9-10 into bits 4-5 (involution, <8KB).
__device__ __forceinline__ int swz(int a) { return a ^ (((a >> 9) & 3) << 4); }

// Fused preprocessing:
//  blocks [0,4096):  x fp32 NCHW -> xThi/xTlo bf16 [b][px][cin]
//  blocks [4096,4312): weight prep
__global__ __launch_bounds__(256) void pre_kernel(const float* __restrict__ x,
                                                  const float* __restrict__ wo,
                                                  const float* __restrict__ wd,
                                                  unsigned short* __restrict__ xThi,
                                                  unsigned short* __restrict__ xTlo,
                                                  unsigned short* __restrict__ wdA,
                                                  unsigned short* __restrict__ woAhi,
                                                  unsigned short* __restrict__ woAlo) {
  int tid = threadIdx.x;
  if (blockIdx.x < 4096) {
    __shared__ float tile[32][33];   // [c_local][p_local]
    int t = blockIdx.x;
    int b = t >> 10, rem = t & 1023;
    int c0 = (rem >> 9) * 32, p0 = (rem & 511) * 32;
    int tx = tid & 31, ty = tid >> 5;      // (32,8)
    const float* xb = x + (size_t)b * CIN * HWPIX;
    size_t boff = (size_t)b * HWPIX * CIN;
#pragma unroll
    for (int i = 0; i < 4; i++)
      tile[ty + i * 8][tx] = xb[(size_t)(c0 + ty + i * 8) * HWPIX + p0 + tx];
    __syncthreads();
#pragma unroll
    for (int i = 0; i < 2; i++) {
      int tt = tid + i * 256;       // 0..511 = 32 rows * 16 cin-pairs
      int row = tt >> 4;
      int cp = tt & 15;
      float v0 = tile[cp * 2][row], v1 = tile[cp * 2 + 1][row];
      unsigned short h0 = f2bf(v0), h1 = f2bf(v1);
      unsigned short l0 = f2bf(v0 - bf2f(h0)), l1 = f2bf(v1 - bf2f(h1));
      size_t o = boff + (size_t)(p0 + row) * CIN + c0 + cp * 2;
      *(ushort2*)&xThi[o] = make_ushort2(h0, h1);
      *(ushort2*)&xTlo[o] = make_ushort2(l0, l1);
    }
  } else {
    int t = (blockIdx.x - 4096) * 256 + tid;
    if (t < 36864) {
      int j = t & 7, lane = (t >> 3) & 63, ct = (t >> 9) & 3, kc = (t >> 11) & 1, kk = t >> 12;
      int cout = ct * 16 + (lane & 15);
      int cin  = kc * 32 + (lane >> 4) * 8 + j;
      wdA[t] = f2bf(wd[(size_t)(cout * CIN + cin) * 9 + kk]);
    }
    int t2 = t - 36864;
    if (t2 >= 0 && t2 < 18432) {
      int j = t2 & 7, lane = (t2 >> 3) & 63, ct = (t2 >> 9) & 1, kc = (t2 >> 10) & 1, kk = t2 >> 11;
      int cout = ct * 16 + (lane & 15);          // conv channel 0..31 (valid < 18)
      int cin  = kc * 32 + (lane >> 4) * 8 + j;
      float v = (cout < 18) ? wo[(size_t)(cout * CIN + cin) * 9 + kk] : 0.f;
      unsigned short h = f2bf(v);
      woAhi[t2] = h;
      woAlo[t2] = f2bf(v - bf2f(h));
    }
  }
}

// Fused offset-conv + deform GEMM; double-buffered, 1 barrier per kk.
// Block: 64 px tile (b, y, x0..x0+63), 256 thr = 4 waves.
// Staging view: p1 = tid>>2 (px 0..63), si = tid&3 (16-cin slice).
// MFMA view: wave w, lane.
__global__ __launch_bounds__(256) void fused_dcn_kernel(const unsigned short* __restrict__ xThi,
                                                        const unsigned short* __restrict__ xTlo,
                                                        const unsigned short* __restrict__ woAhi,
                                                        const unsigned short* __restrict__ woAlo,
                                                        const unsigned short* __restrict__ wdA,
                                                        float* __restrict__ out) {
  __shared__ unsigned short sBhi2[2][4096];   // 16 KB; A: im2col hi dbuf; B: sampled dbuf
  __shared__ unsigned short sBlo2[2][4096];   // 16 KB; A only: im2col lo dbuf
  __shared__ float offL[18 * 64];             // 4.5 KB
  char* sHc = (char*)sBhi2;
  char* sLc = (char*)sBlo2;

  int tid = threadIdx.x;
  int hw = blockIdx.x;
  int bid = (hw & 7) * 128 + (hw >> 3);    // XCD-contiguous y bands
  int b = bid >> 8, r = bid & 255, y = r >> 1, x0 = (r & 1) << 6;

  int p1 = tid >> 2, si = tid & 3;
  int lane = tid & 63, w = tid >> 6;

  const unsigned short* xhib = xThi + (size_t)b * HWPIX * CIN;
  const unsigned short* xlob = xTlo + (size_t)b * HWPIX * CIN;

  // staging byte offsets (within one 8 KB buffer), swizzled once
  int wq = p1 >> 4, iq = p1 & 15;
  int kcd = si >> 1, qb = si & 1;
  int wb0 = ((((wq * 2 + kcd) * 64) + qb * 32 + iq) * 8) * 2;
  int wb1 = wb0 + 256;
  int swb0 = swz(wb0), swb1 = swz(wb1);
  int srb0 = swz((w * 2 + 0) * 1024 + lane * 16);
  int srb1 = swz((w * 2 + 1) * 1024 + lane * 16);

  int xp = x0 + p1;

  // ================= Phase A: offset conv (dbuf, 1 barrier/kk) =============
  floatx4 oacc[2];
  oacc[0] = (floatx4){0.f, 0.f, 0.f, 0.f};
  oacc[1] = (floatx4){0.f, 0.f, 0.f, 0.f};

  auto ldA = [&](int kk, uint4& h0, uint4& h1, uint4& l0, uint4& l1) {
    int ys = y - 1 + kk / 3;
    int xs = xp - 1 + kk % 3;
    bool valid = (ys >= 0) && (ys < HH) && (xs >= 0) && (xs < WW);
    h0 = (uint4){0, 0, 0, 0}; h1 = h0; l0 = h0; l1 = h0;
    if (valid) {
      const unsigned short* ph = xhib + (size_t)(ys * WW + xs) * CIN + si * 16;
      const unsigned short* pl = xlob + (size_t)(ys * WW + xs) * CIN + si * 16;
      h0 = *(const uint4*)ph; h1 = *(const uint4*)(ph + 8);
      l0 = *(const uint4*)pl; l1 = *(const uint4*)(pl + 8);
    }
  };
  auto stageA = [&](int nxt, const uint4& h0, const uint4& h1, const uint4& l0, const uint4& l1) {
    *(uint4*)(sHc + nxt * 8192 + swb0) = h0;
    *(uint4*)(sHc + nxt * 8192 + swb1) = h1;
    *(uint4*)(sLc + nxt * 8192 + swb0) = l0;
    *(uint4*)(sLc + nxt * 8192 + swb1) = l1;
  };
  auto mfmaA = [&](int kk, int cur) {
    const short8* Ah = (const short8*)(woAhi + (size_t)kk * 2048);
    const short8* Al = (const short8*)(woAlo + (size_t)kk * 2048);
    short8 ah0a = Ah[lane],       ah1a = Ah[128 + lane];
    short8 al0a = Al[lane],       al1a = Al[128 + lane];
    short8 ah0b = Ah[64 + lane],  ah1b = Ah[192 + lane];
    short8 al0b = Al[64 + lane],  al1b = Al[192 + lane];
    short8 bh0 = *(const short8*)(sHc + cur * 8192 + srb0);
    short8 bh1 = *(const short8*)(sHc + cur * 8192 + srb1);
    short8 bl0 = *(const short8*)(sLc + cur * 8192 + srb0);
    short8 bl1 = *(const short8*)(sLc + cur * 8192 + srb1);
    oacc[0] = __builtin_amdgcn_mfma_f32_16x16x32_bf16(ah0a, bh0, oacc[0], 0, 0, 0);
    oacc[0] = __builtin_amdgcn_mfma_f32_16x16x32_bf16(ah0a, bl0, oacc[0], 0, 0, 0);
    oacc[0] = __builtin_amdgcn_mfma_f32_16x16x32_bf16(al0a, bh0, oacc[0], 0, 0, 0);
    oacc[0] = __builtin_amdgcn_mfma_f32_16x16x32_bf16(ah1a, bh1, oacc[0], 0, 0, 0);
    oacc[0] = __builtin_amdgcn_mfma_f32_16x16x32_bf16(ah1a, bl1, oacc[0], 0, 0, 0);
    oacc[0] = __builtin_amdgcn_mfma_f32_16x16x32_bf16(al1a, bh1, oacc[0], 0, 0, 0);
    oacc[1] = __builtin_amdgcn_mfma_f32_16x16x32_bf16(ah0b, bh0, oacc[1], 0, 0, 0);
    oacc[1] = __builtin_amdgcn_mfma_f32_16x16x32_bf16(ah0b, bl0, oacc[1], 0, 0, 0);
    oacc[1] = __builtin_amdgcn_mfma_f32_16x16x32_bf16(al0b, bh0, oacc[1], 0, 0, 0);
    oacc[1] = __builtin_amdgcn_mfma_f32_16x16x32_bf16(ah1b, bh1, oacc[1], 0, 0, 0);
    oacc[1] = __builtin_amdgcn_mfma_f32_16x16x32_bf16(ah1b, bl1, oacc[1], 0, 0, 0);
    oacc[1] = __builtin_amdgcn_mfma_f32_16x16x32_bf16(al1b, bh1, oacc[1], 0, 0, 0);
  };

  {
    uint4 h0c, h1c, l0c, l1c;
    ldA(0, h0c, h1c, l0c, l1c);
    stageA(0, h0c, h1c, l0c, l1c);
    __syncthreads();
#pragma unroll 1
    for (int kk = 0; kk < 9; kk++) {
      uint4 h0n, h1n, l0n, l1n;
      if (kk < 8) ldA(kk + 1, h0n, h1n, l0n, l1n);   // issue gathers early
      mfmaA(kk, kk & 1);                             // consume cur buffer
      if (kk < 8) stageA((kk + 1) & 1, h0n, h1n, l0n, l1n);
      __syncthreads();                               // next buf ready / cur free
    }
  }

  // Scatter offsets to LDS. D layout: col=lane&15 (px), row=(lane>>4)*4+rr.
  // Wave w writes columns [16w,16w+16); phase B (p1 in [16w,16w+16)) reads
  // only those -> same-wave ordering, no extra barrier needed.
  {
    int pxl = w * 16 + (lane & 15);
    int rowb = (lane >> 4) * 4;
#pragma unroll
    for (int ct = 0; ct < 2; ct++)
#pragma unroll
      for (int rr = 0; rr < 4; rr++) {
        int row = ct * 16 + rowb + rr;
        if (row < 18) offL[row * 64 + pxl] = oacc[ct][rr];
      }
  }

  // ================= Phase B: deform sample + GEMM (dbuf, 1 barrier/kk) =====
  floatx4 acc[4];
#pragma unroll
  for (int ct = 0; ct < 4; ct++) acc[ct] = (floatx4){0.f, 0.f, 0.f, 0.f};

  struct BS {
    float w00, w01, w10, w11;
    uint4 a00, a01, a10, a11, b00, b01, b10, b11;
  };
  auto ldB = [&](int kk) -> BS {
    BS s;
    float dy = offL[(2 * kk) * 64 + p1];
    float dx = offL[(2 * kk + 1) * 64 + p1];
    float ys = (float)(y - 1 + kk / 3) + dy;
    float xs = (float)(xp - 1 + kk % 3) + dx;
    float y0f = floorf(ys), x0f = floorf(xs);
    float wy = ys - y0f, wx = xs - x0f;
    int iy0 = (int)y0f, ix0 = (int)x0f;
    int iy1 = iy0 + 1, ix1 = ix0 + 1;
    s.w00 = (1.f - wy) * (1.f - wx); s.w01 = (1.f - wy) * wx;
    s.w10 = wy * (1.f - wx);         s.w11 = wy * wx;
    bool vy0 = (iy0 >= 0) && (iy0 < HH), vy1 = (iy1 >= 0) && (iy1 < HH);
    bool vx0 = (ix0 >= 0) && (ix0 < WW), vx1 = (ix1 >= 0) && (ix1 < WW);
    if (!(vy0 && vx0)) s.w00 = 0.f;
    if (!(vy0 && vx1)) s.w01 = 0.f;
    if (!(vy1 && vx0)) s.w10 = 0.f;
    if (!(vy1 && vx1)) s.w11 = 0.f;
    int cy0 = min(max(iy0, 0), HH - 1), cy1 = min(max(iy1, 0), HH - 1);
    int cx0 = min(max(ix0, 0), WW - 1), cx1 = min(max(ix1, 0), WW - 1);
    const unsigned short* q00 = xhib + (size_t)(cy0 * WW + cx0) * CIN + si * 16;
    const unsigned short* q01 = xhib + (size_t)(cy0 * WW + cx1) * CIN + si * 16;
    const unsigned short* q10 = xhib + (size_t)(cy1 * WW + cx0) * CIN + si * 16;
    const unsigned short* q11 = xhib + (size_t)(cy1 * WW + cx1) * CIN + si * 16;
    s.a00 = *(const uint4*)q00; s.a01 = *(const uint4*)q01;
    s.a10 = *(const uint4*)q10; s.a11 = *(const uint4*)q11;
    s.b00 = *(const uint4*)(q00 + 8); s.b01 = *(const uint4*)(q01 + 8);
    s.b10 = *(const uint4*)(q10 + 8); s.b11 = *(const uint4*)(q11 + 8);
    return s;
  };
  auto blendStoreB = [&](int nxt, const BS& s) {
    uint4 o0, o1;
    o0.x = bilin2(s.a00.x, s.a01.x, s.a10.x, s.a11.x, s.w00, s.w01, s.w10, s.w11);
    o0.y = bilin2(s.a00.y, s.a01.y, s.a10.y, s.a11.y, s.w00, s.w01, s.w10, s.w11);
    o0.z = bilin2(s.a00.z, s.a01.z, s.a10.z, s.a11.z, s.w00, s.w01, s.w10, s.w11);
    o0.w = bilin2(s.a00.w, s.a01.w, s.a10.w, s.a11.w, s.w00, s.w01, s.w10, s.w11);
    o1.x = bilin2(s.b00.x, s.b01.x, s.b10.x, s.b11.x, s.w00, s.w01, s.w10, s.w11);
    o1.y = bilin2(s.b00.y, s.b01.y, s.b10.y, s.b11.y, s.w00, s.w01, s.w10, s.w11);
    o1.z = bilin2(s.b00.z, s.b01.z, s.b10.z, s.b11.z, s.w00, s.w01, s.w10, s.w11);
    o1.w = bilin2(s.b00.w, s.b01.w, s.b10.w, s.b11.w, s.w00, s.w01, s.w10, s.w11);
    *(uint4*)(sHc + nxt * 8192 + swb0) = o0;
    *(uint4*)(sHc + nxt * 8192 + swb1) = o1;
  };
  auto mfmaB = [&](int kk, int cur) {
    const short8* Ap = (const short8*)(wdA + (size_t)kk * 4096);
    short8 a0q0 = Ap[lane],        a1q0 = Ap[256 + lane];
    short8 a0q1 = Ap[64 + lane],   a1q1 = Ap[320 + lane];
    short8 a0q2 = Ap[128 + lane],  a1q2 = Ap[384 + lane];
    short8 a0q3 = Ap[192 + lane],  a1q3 = Ap[448 + lane];
    short8 bv0 = *(const short8*)(sHc + cur * 8192 + srb0);
    short8 bv1 = *(const short8*)(sHc + cur * 8192 + srb1);
    acc[0] = __builtin_amdgcn_mfma_f32_16x16x32_bf16(a0q0, bv0, acc[0], 0, 0, 0);
    acc[0] = __builtin_amdgcn_mfma_f32_16x16x32_bf16(a1q0, bv1, acc[0], 0, 0, 0);
    acc[1] = __builtin_amdgcn_mfma_f32_16x16x32_bf16(a0q1, bv0, acc[1], 0, 0, 0);
    acc[1] = __builtin_amdgcn_mfma_f32_16x16x32_bf16(a1q1, bv1, acc[1], 0, 0, 0);
    acc[2] = __builtin_amdgcn_mfma_f32_16x16x32_bf16(a0q2, bv0, acc[2], 0, 0, 0);
    acc[2] = __builtin_amdgcn_mfma_f32_16x16x32_bf16(a1q2, bv1, acc[2], 0, 0, 0);
    acc[3] = __builtin_amdgcn_mfma_f32_16x16x32_bf16(a0q3, bv0, acc[3], 0, 0, 0);
    acc[3] = __builtin_amdgcn_mfma_f32_16x16x32_bf16(a1q3, bv1, acc[3], 0, 0, 0);
  };

  {
    // prologue: stage kk=0 into buf0 (phase A's final barrier above makes
    // the sHc alias safe: all waves are done reading phase-A buffers)
    BS s0 = ldB(0);
    blendStoreB(0, s0);
    __syncthreads();
#pragma unroll 1
    for (int kk = 0; kk < 9; kk++) {
      BS sn;
      if (kk < 8) sn = ldB(kk + 1);          // issue gathers early
      mfmaB(kk, kk & 1);                     // consume cur buffer
      if (kk < 8) blendStoreB((kk + 1) & 1, sn);
      __syncthreads();                       // next buf ready / cur free
    }
  }

  // D: col = lane&15 (px in wave tile), row = (lane>>4)*4 + reg (cout in ct tile)
  int px = x0 + w * 16 + (lane & 15);
  int rowb = (lane >> 4) * 4;
  float* outb = out + (size_t)b * COUT * HWPIX + y * WW + px;
#pragma unroll
  for (int ct = 0; ct < 4; ct++)
#pragma unroll
    for (int rr = 0; rr < 4; rr++)
      outb[(size_t)(ct * 16 + rowb + rr) * HWPIX] = acc[ct][rr];
}

extern "C" void kernel_launch(void* const* d_in, const int* in_sizes, int n_in,
                              void* d_out, int out_size, void* d_ws, size_t ws_size,
                              hipStream_t stream) {
  const float* x  = (const float*)d_in[0];
  const float* wo = (const float*)d_in[1];
  const float* wd = (const float*)d_in[2];
  float* out = (float*)d_out;

  char* wsb = (char*)d_ws;
  unsigned short* xThi  = (unsigned short*)wsb;                         // 8,388,608 B
  unsigned short* xTlo  = (unsigned short*)(wsb + 8388608);             // 8,388,608 B
  unsigned short* wdA   = (unsigned short*)(wsb + 16777216);            // 73,728 B
  unsigned short* woAhi = (unsigned short*)(wsb + 16777216 + 73728);    // 36,864 B
  unsigned short* woAlo = (unsigned short*)(wsb + 16850944 + 36864);    // 36,864 B

  pre_kernel<<<dim3(4096 + 216), dim3(256), 0, stream>>>(x, wo, wd, xThi, xTlo, wdA, woAhi, woAlo);
  fused_dcn_kernel<<<dim3(BATCH * HWPIX / 64), dim3(256), 0, stream>>>(xThi, xTlo, woAhi, woAlo, wdA, out);
}

// Round 9
// 105.988 us; speedup vs baseline: 1.3561x; 1.0934x over previous
//
#include <hip/hip_runtime.h>

// DCNv2, fp32 in/out, all matmul-shaped work on bf16 MFMA.
// Round 9: wave -> cout-tile remap (A-frag dedup). In R8 all 4 waves loaded
// IDENTICAL A-fragments from global every kk (TCP bytes: 128KB/CU/iter for
// A alone). Now wave w owns cout tile ct=w (phase B; ct=w&1 for phase A)
// and loops over the 4 px-group B-frags from LDS instead. A-frag global
// traffic /4 (B) and /2 (A); B LDS reads grow (LDS pipe idle). Arithmetic
// order per output element unchanged -> bit-identical.
// Keeps R8: dbuf staging 1 barrier/kk, cvt_pk pack, LDS swizzle.
// ws: xThi 8388608 | xTlo 8388608 | wdA 73728 | woAhi 36864 | woAlo 36864

#define BATCH 4
#define CIN   64
#define COUT  64
#define HH    128
#define WW    128
#define HWPIX (HH*WW)

typedef __attribute__((ext_vector_type(8))) short short8;   // 8 bf16 (4 VGPRs)
typedef __attribute__((ext_vector_type(4))) float floatx4;  // MFMA C/D

__device__ __forceinline__ unsigned short f2bf(float f) {   // RNE f32->bf16
  unsigned int u = __float_as_uint(f);
  unsigned int r = u + 0x7fffu + ((u >> 16) & 1u);
  return (unsigned short)(r >> 16);
}
__device__ __forceinline__ float bf2f(unsigned short h) { return __uint_as_float(((unsigned int)h) << 16); }
__device__ __forceinline__ float lo16f(unsigned int u) { return __uint_as_float(u << 16); }
__device__ __forceinline__ float hi16f(unsigned int u) { return __uint_as_float(u & 0xffff0000u); }

// 2-channel bilinear blend; pack via HW RNE convert (== f2bf pair).
__device__ __forceinline__ unsigned int bilin2(unsigned int u00, unsigned int u01,
                                               unsigned int u10, unsigned int u11,
                                               float w00, float w01, float w10, float w11) {
  float lo = w00 * lo16f(u00) + w01 * lo16f(u01) + w10 * lo16f(u10) + w11 * lo16f(u11);
  float hi = w00 * hi16f(u00) + w01 * hi16f(u01) + w10 * hi16f(u10) + w11 * hi16f(u11);
  unsigned int r;
  asm("v_cvt_pk_bf16_f32 %0, %1, %2" : "=v"(r) : "v"(lo), "v"(hi));
  return r;
}

// LDS byte-offset swizzle: fold bits 9-10 into bits 4-5 (involution, <8KB).
__device__ __forceinline__ int swz(int a) { return a ^ (((a >> 9) & 3) << 4); }

// Fused preprocessing:
//  blocks [0,4096):  x fp32 NCHW -> xThi/xTlo bf16 [b][px][cin]
//  blocks [4096,4312): weight prep
__global__ __launch_bounds__(256) void pre_kernel(const float* __restrict__ x,
                                                  const float* __restrict__ wo,
                                                  const float* __restrict__ wd,
                                                  unsigned short* __restrict__ xThi,
                                                  unsigned short* __restrict__ xTlo,
                                                  unsigned short* __restrict__ wdA,
                                                  unsigned short* __restrict__ woAhi,
                                                  unsigned short* __restrict__ woAlo) {
  int tid = threadIdx.x;
  if (blockIdx.x < 4096) {
    __shared__ float tile[32][33];   // [c_local][p_local]
    int t = blockIdx.x;
    int b = t >> 10, rem = t & 1023;
    int c0 = (rem >> 9) * 32, p0 = (rem & 511) * 32;
    int tx = tid & 31, ty = tid >> 5;      // (32,8)
    const float* xb = x + (size_t)b * CIN * HWPIX;
    size_t boff = (size_t)b * HWPIX * CIN;
#pragma unroll
    for (int i = 0; i < 4; i++)
      tile[ty + i * 8][tx] = xb[(size_t)(c0 + ty + i * 8) * HWPIX + p0 + tx];
    __syncthreads();
#pragma unroll
    for (int i = 0; i < 2; i++) {
      int tt = tid + i * 256;       // 0..511 = 32 rows * 16 cin-pairs
      int row = tt >> 4;
      int cp = tt & 15;
      float v0 = tile[cp * 2][row], v1 = tile[cp * 2 + 1][row];
      unsigned short h0 = f2bf(v0), h1 = f2bf(v1);
      unsigned short l0 = f2bf(v0 - bf2f(h0)), l1 = f2bf(v1 - bf2f(h1));
      size_t o = boff + (size_t)(p0 + row) * CIN + c0 + cp * 2;
      *(ushort2*)&xThi[o] = make_ushort2(h0, h1);
      *(ushort2*)&xTlo[o] = make_ushort2(l0, l1);
    }
  } else {
    int t = (blockIdx.x - 4096) * 256 + tid;
    if (t < 36864) {
      int j = t & 7, lane = (t >> 3) & 63, ct = (t >> 9) & 3, kc = (t >> 11) & 1, kk = t >> 12;
      int cout = ct * 16 + (lane & 15);
      int cin  = kc * 32 + (lane >> 4) * 8 + j;
      wdA[t] = f2bf(wd[(size_t)(cout * CIN + cin) * 9 + kk]);
    }
    int t2 = t - 36864;
    if (t2 >= 0 && t2 < 18432) {
      int j = t2 & 7, lane = (t2 >> 3) & 63, ct = (t2 >> 9) & 1, kc = (t2 >> 10) & 1, kk = t2 >> 11;
      int cout = ct * 16 + (lane & 15);          // conv channel 0..31 (valid < 18)
      int cin  = kc * 32 + (lane >> 4) * 8 + j;
      float v = (cout < 18) ? wo[(size_t)(cout * CIN + cin) * 9 + kk] : 0.f;
      unsigned short h = f2bf(v);
      woAhi[t2] = h;
      woAlo[t2] = f2bf(v - bf2f(h));
    }
  }
}

// Fused offset-conv + deform GEMM; dbuf 1 barrier/kk; wave = cout tile.
// Block: 64 px tile (b, y, x0..x0+63), 256 thr = 4 waves.
// Staging view: p1 = tid>>2 (px 0..63), si = tid&3 (16-cin slice).
// MFMA view phase A: wave w -> ct=w&1, px-groups {2*(w>>1), 2*(w>>1)+1}.
// MFMA view phase B: wave w -> ct=w (couts 16w..16w+16), px-groups 0..3.
__global__ __launch_bounds__(256) void fused_dcn_kernel(const unsigned short* __restrict__ xThi,
                                                        const unsigned short* __restrict__ xTlo,
                                                        const unsigned short* __restrict__ woAhi,
                                                        const unsigned short* __restrict__ woAlo,
                                                        const unsigned short* __restrict__ wdA,
                                                        float* __restrict__ out) {
  __shared__ unsigned short sBhi2[2][4096];   // 16 KB; A: im2col hi dbuf; B: sampled dbuf
  __shared__ unsigned short sBlo2[2][4096];   // 16 KB; A only: im2col lo dbuf
  __shared__ float offL[18 * 64];             // 4.5 KB
  char* sHc = (char*)sBhi2;
  char* sLc = (char*)sBlo2;

  int tid = threadIdx.x;
  int hw = blockIdx.x;
  int bid = (hw & 7) * 128 + (hw >> 3);    // XCD-contiguous y bands
  int b = bid >> 8, r = bid & 255, y = r >> 1, x0 = (r & 1) << 6;

  int p1 = tid >> 2, si = tid & 3;
  int lane = tid & 63, w = tid >> 6;

  const unsigned short* xhib = xThi + (size_t)b * HWPIX * CIN;
  const unsigned short* xlob = xTlo + (size_t)b * HWPIX * CIN;

  // staging byte offsets (within one 8 KB buffer), swizzled once
  int wq = p1 >> 4, iq = p1 & 15;
  int kcd = si >> 1, qb = si & 1;
  int wb0 = ((((wq * 2 + kcd) * 64) + qb * 32 + iq) * 8) * 2;
  int wb1 = wb0 + 256;
  int swb0 = swz(wb0), swb1 = swz(wb1);
  // read offsets per px-group pg: (pg, kc=0) and (pg, kc=1)
  int brb0[4], brb1[4];
#pragma unroll
  for (int pg = 0; pg < 4; pg++) {
    brb0[pg] = swz(pg * 2048 + lane * 16);
    brb1[pg] = swz(pg * 2048 + 1024 + lane * 16);
  }

  int xp = x0 + p1;

  // ================= Phase A: offset conv (dbuf, wave=ct/px-half) ==========
  floatx4 oacc[2];   // indexed by pgi (px-group within this wave's pair)
  oacc[0] = (floatx4){0.f, 0.f, 0.f, 0.f};
  oacc[1] = (floatx4){0.f, 0.f, 0.f, 0.f};
  int ctA = w & 1, pgA = (w >> 1) * 2;

  auto ldA = [&](int kk, uint4& h0, uint4& h1, uint4& l0, uint4& l1) {
    int ys = y - 1 + kk / 3;
    int xs = xp - 1 + kk % 3;
    bool valid = (ys >= 0) && (ys < HH) && (xs >= 0) && (xs < WW);
    h0 = (uint4){0, 0, 0, 0}; h1 = h0; l0 = h0; l1 = h0;
    if (valid) {
      const unsigned short* ph = xhib + (size_t)(ys * WW + xs) * CIN + si * 16;
      const unsigned short* pl = xlob + (size_t)(ys * WW + xs) * CIN + si * 16;
      h0 = *(const uint4*)ph; h1 = *(const uint4*)(ph + 8);
      l0 = *(const uint4*)pl; l1 = *(const uint4*)(pl + 8);
    }
  };
  auto stageA = [&](int nxt, const uint4& h0, const uint4& h1, const uint4& l0, const uint4& l1) {
    *(uint4*)(sHc + nxt * 8192 + swb0) = h0;
    *(uint4*)(sHc + nxt * 8192 + swb1) = h1;
    *(uint4*)(sLc + nxt * 8192 + swb0) = l0;
    *(uint4*)(sLc + nxt * 8192 + swb1) = l1;
  };
  auto mfmaA = [&](int kk, int cur) {
    const short8* Ah = (const short8*)(woAhi + (size_t)kk * 2048);
    const short8* Al = (const short8*)(woAlo + (size_t)kk * 2048);
    short8 ah0 = Ah[ctA * 64 + lane], ah1 = Ah[128 + ctA * 64 + lane];
    short8 al0 = Al[ctA * 64 + lane], al1 = Al[128 + ctA * 64 + lane];
#pragma unroll
    for (int pgi = 0; pgi < 2; pgi++) {
      int pg = pgA + pgi;
      short8 bh0 = *(const short8*)(sHc + cur * 8192 + brb0[pg]);
      short8 bh1 = *(const short8*)(sHc + cur * 8192 + brb1[pg]);
      short8 bl0 = *(const short8*)(sLc + cur * 8192 + brb0[pg]);
      short8 bl1 = *(const short8*)(sLc + cur * 8192 + brb1[pg]);
      oacc[pgi] = __builtin_amdgcn_mfma_f32_16x16x32_bf16(ah0, bh0, oacc[pgi], 0, 0, 0);
      oacc[pgi] = __builtin_amdgcn_mfma_f32_16x16x32_bf16(ah0, bl0, oacc[pgi], 0, 0, 0);
      oacc[pgi] = __builtin_amdgcn_mfma_f32_16x16x32_bf16(al0, bh0, oacc[pgi], 0, 0, 0);
      oacc[pgi] = __builtin_amdgcn_mfma_f32_16x16x32_bf16(ah1, bh1, oacc[pgi], 0, 0, 0);
      oacc[pgi] = __builtin_amdgcn_mfma_f32_16x16x32_bf16(ah1, bl1, oacc[pgi], 0, 0, 0);
      oacc[pgi] = __builtin_amdgcn_mfma_f32_16x16x32_bf16(al1, bh1, oacc[pgi], 0, 0, 0);
    }
  };

  {
    uint4 h0c, h1c, l0c, l1c;
    ldA(0, h0c, h1c, l0c, l1c);
    stageA(0, h0c, h1c, l0c, l1c);
    __syncthreads();
#pragma unroll 1
    for (int kk = 0; kk < 9; kk++) {
      uint4 h0n, h1n, l0n, l1n;
      if (kk < 8) ldA(kk + 1, h0n, h1n, l0n, l1n);   // issue gathers early
      mfmaA(kk, kk & 1);                             // consume cur buffer
      if (kk < 8) stageA((kk + 1) & 1, h0n, h1n, l0n, l1n);
      __syncthreads();                               // next buf ready / cur free
    }
  }

  // Scatter offsets to LDS. Wave w holds ct=ctA rows for px-groups pgA,pgA+1;
  // phase B reads offL by p1 across all px -> cross-wave: barrier after.
  {
    int rowb = (lane >> 4) * 4;
    int colb = pgA * 16 + (lane & 15);
#pragma unroll
    for (int pgi = 0; pgi < 2; pgi++)
#pragma unroll
      for (int rr = 0; rr < 4; rr++) {
        int row = ctA * 16 + rowb + rr;
        if (row < 18) offL[row * 64 + colb + pgi * 16] = oacc[pgi][rr];
      }
  }
  __syncthreads();

  // ================= Phase B: deform sample + GEMM (dbuf, wave=ct) =========
  floatx4 acc[4];   // indexed by px-group pg; couts [16w,16w+16)
#pragma unroll
  for (int pg = 0; pg < 4; pg++) acc[pg] = (floatx4){0.f, 0.f, 0.f, 0.f};

  struct BS {
    float w00, w01, w10, w11;
    uint4 a00, a01, a10, a11, b00, b01, b10, b11;
  };
  auto ldB = [&](int kk) -> BS {
    BS s;
    float dy = offL[(2 * kk) * 64 + p1];
    float dx = offL[(2 * kk + 1) * 64 + p1];
    float ys = (float)(y - 1 + kk / 3) + dy;
    float xs = (float)(xp - 1 + kk % 3) + dx;
    float y0f = floorf(ys), x0f = floorf(xs);
    float wy = ys - y0f, wx = xs - x0f;
    int iy0 = (int)y0f, ix0 = (int)x0f;
    int iy1 = iy0 + 1, ix1 = ix0 + 1;
    s.w00 = (1.f - wy) * (1.f - wx); s.w01 = (1.f - wy) * wx;
    s.w10 = wy * (1.f - wx);         s.w11 = wy * wx;
    bool vy0 = (iy0 >= 0) && (iy0 < HH), vy1 = (iy1 >= 0) && (iy1 < HH);
    bool vx0 = (ix0 >= 0) && (ix0 < WW), vx1 = (ix1 >= 0) && (ix1 < WW);
    if (!(vy0 && vx0)) s.w00 = 0.f;
    if (!(vy0 && vx1)) s.w01 = 0.f;
    if (!(vy1 && vx0)) s.w10 = 0.f;
    if (!(vy1 && vx1)) s.w11 = 0.f;
    int cy0 = min(max(iy0, 0), HH - 1), cy1 = min(max(iy1, 0), HH - 1);
    int cx0 = min(max(ix0, 0), WW - 1), cx1 = min(max(ix1, 0), WW - 1);
    const unsigned short* q00 = xhib + (size_t)(cy0 * WW + cx0) * CIN + si * 16;
    const unsigned short* q01 = xhib + (size_t)(cy0 * WW + cx1) * CIN + si * 16;
    const unsigned short* q10 = xhib + (size_t)(cy1 * WW + cx0) * CIN + si * 16;
    const unsigned short* q11 = xhib + (size_t)(cy1 * WW + cx1) * CIN + si * 16;
    s.a00 = *(const uint4*)q00; s.a01 = *(const uint4*)q01;
    s.a10 = *(const uint4*)q10; s.a11 = *(const uint4*)q11;
    s.b00 = *(const uint4*)(q00 + 8); s.b01 = *(const uint4*)(q01 + 8);
    s.b10 = *(const uint4*)(q10 + 8); s.b11 = *(const uint4*)(q11 + 8);
    return s;
  };
  auto blendStoreB = [&](int nxt, const BS& s) {
    uint4 o0, o1;
    o0.x = bilin2(s.a00.x, s.a01.x, s.a10.x, s.a11.x, s.w00, s.w01, s.w10, s.w11);
    o0.y = bilin2(s.a00.y, s.a01.y, s.a10.y, s.a11.y, s.w00, s.w01, s.w10, s.w11);
    o0.z = bilin2(s.a00.z, s.a01.z, s.a10.z, s.a11.z, s.w00, s.w01, s.w10, s.w11);
    o0.w = bilin2(s.a00.w, s.a01.w, s.a10.w, s.a11.w, s.w00, s.w01, s.w10, s.w11);
    o1.x = bilin2(s.b00.x, s.b01.x, s.b10.x, s.b11.x, s.w00, s.w01, s.w10, s.w11);
    o1.y = bilin2(s.b00.y, s.b01.y, s.b10.y, s.b11.y, s.w00, s.w01, s.w10, s.w11);
    o1.z = bilin2(s.b00.z, s.b01.z, s.b10.z, s.b11.z, s.w00, s.w01, s.w10, s.w11);
    o1.w = bilin2(s.b00.w, s.b01.w, s.b10.w, s.b11.w, s.w00, s.w01, s.w10, s.w11);
    *(uint4*)(sHc + nxt * 8192 + swb0) = o0;
    *(uint4*)(sHc + nxt * 8192 + swb1) = o1;
  };
  auto mfmaB = [&](int kk, int cur) {
    const short8* Ap = (const short8*)(wdA + (size_t)kk * 4096);
    short8 a0 = Ap[w * 64 + lane];          // this wave's ct only (A dedup)
    short8 a1 = Ap[256 + w * 64 + lane];
#pragma unroll
    for (int pg = 0; pg < 4; pg++) {
      short8 bv0 = *(const short8*)(sHc + cur * 8192 + brb0[pg]);
      short8 bv1 = *(const short8*)(sHc + cur * 8192 + brb1[pg]);
      acc[pg] = __builtin_amdgcn_mfma_f32_16x16x32_bf16(a0, bv0, acc[pg], 0, 0, 0);
      acc[pg] = __builtin_amdgcn_mfma_f32_16x16x32_bf16(a1, bv1, acc[pg], 0, 0, 0);
    }
  };

  {
    BS s0 = ldB(0);
    blendStoreB(0, s0);
    __syncthreads();
#pragma unroll 1
    for (int kk = 0; kk < 9; kk++) {
      BS sn;
      if (kk < 8) sn = ldB(kk + 1);          // issue gathers early
      mfmaB(kk, kk & 1);                     // consume cur buffer
      if (kk < 8) blendStoreB((kk + 1) & 1, sn);
      __syncthreads();                       // next buf ready / cur free
    }
  }

  // D: col = lane&15 (px within pg tile), row = (lane>>4)*4 + reg;
  // wave w owns couts [16w, 16w+16) for all 4 px-groups.
  int rowb = (lane >> 4) * 4;
  float* outb = out + (size_t)b * COUT * HWPIX + y * WW + x0 + (lane & 15);
#pragma unroll
  for (int pg = 0; pg < 4; pg++)
#pragma unroll
    for (int rr = 0; rr < 4; rr++)
      outb[(size_t)(w * 16 + rowb + rr) * HWPIX + pg * 16] = acc[pg][rr];
}

extern "C" void kernel_launch(void* const* d_in, const int* in_sizes, int n_in,
                              void* d_out, int out_size, void* d_ws, size_t ws_size,
                              hipStream_t stream) {
  const float* x  = (const float*)d_in[0];
  const float* wo = (const float*)d_in[1];
  const float* wd = (const float*)d_in[2];
  float* out = (float*)d_out;

  char* wsb = (char*)d_ws;
  unsigned short* xThi  = (unsigned short*)wsb;                         // 8,388,608 B
  unsigned short* xTlo  = (unsigned short*)(wsb + 8388608);             // 8,388,608 B
  unsigned short* wdA   = (unsigned short*)(wsb + 16777216);            // 73,728 B
  unsigned short* woAhi = (unsigned short*)(wsb + 16777216 + 73728);    // 36,864 B
  unsigned short* woAlo = (unsigned short*)(wsb + 16850944 + 36864);    // 36,864 B

  pre_kernel<<<dim3(4096 + 216), dim3(256), 0, stream>>>(x, wo, wd, xThi, xTlo, wdA, woAhi, woAlo);
  fused_dcn_kernel<<<dim3(BATCH * HWPIX / 64), dim3(256), 0, stream>>>(xThi, xTlo, woAhi, woAlo, wdA, out);
}